// Round 1
// baseline (501.052 us; speedup 1.0000x reference)
//
#include <hip/hip_runtime.h>

// IterNorm (ZCA whitening via Newton-Schulz) for X[64,256,56,56] fp32, d=64, g=4, T=10.
//
// Pipeline:
//  K1 cov_kernel    : fused mean+covariance partials, bf16 MFMA SYRK (HBM-bound)
//  K2 reduce_kernel : reduce partials -> mean, Sigma = cross/m - mu mu^T + eps I
//  K3 newton_kernel : 10 Newton iters per group, split-bf16 (hi/lo) MFMA, 4 blocks
//  K4 apply_kernel  : out = (wm @ (x-mean)) * weight + bias, bf16 MFMA, wm in regs
//
// MFMA shape 16x16x32 bf16. Layouts (guide-verified):
//   A: lane l holds A[m=l&15][k=(l>>4)*8+j], j=0..7 (contiguous k -> b64/b128 loads)
//   B: lane l holds B[k=(l>>4)*8+j][n=l&15]  (read as row n of B^T; symmetric operands
//      or transposed-staged tiles make this a contiguous row read)
//   C/D: lane l reg r -> row=(l>>4)*4+r, col=l&15

#define HWSZ 3136
#define NB 64
#define CCH 256
#define DCH 64
#define MTOT (NB * HWSZ) /* 200704 */
#define EPSV 1e-5f
#define TSTRIDE 68  /* bf16 tile row stride (elements); b64 accesses hit 4-way floor = free */
#define NSTRIDE 68  /* newton interleaved-dword row stride */

typedef __attribute__((ext_vector_type(8))) short short8v;
typedef __attribute__((ext_vector_type(4))) float floatx4;

union F8U {
  short8v v;
  unsigned u[4];
  uint2 u2[2];
};

// round-to-nearest-even fp32 -> bf16 bits
__device__ __forceinline__ unsigned short f2bf(float f) {
  unsigned u = __float_as_uint(f);
  u += 0x7fffu + ((u >> 16) & 1u);
  return (unsigned short)(u >> 16);
}

// pack f as hi-bf16 (low half) + residual lo-bf16 (high half) in one dword
__device__ __forceinline__ unsigned pack_hl(float f) {
  unsigned u = __float_as_uint(f);
  unsigned r = u + 0x7fffu + ((u >> 16) & 1u);
  unsigned hbits = r & 0xffff0000u;  // hi as fp32 bits
  float lo = f - __uint_as_float(hbits);
  unsigned ul = __float_as_uint(lo);
  ul += 0x7fffu + ((ul >> 16) & 1u);
  return (hbits >> 16) | (ul & 0xffff0000u);
}

__device__ __forceinline__ float unpack_f(unsigned d) {
  return __uint_as_float(d << 16) + __uint_as_float(d & 0xffff0000u);
}

__device__ __forceinline__ void unpack8(const unsigned* p, short8v& hi, short8v& lo) {
  F8U h, l;
#pragma unroll
  for (int j = 0; j < 4; j++) {
    unsigned d0 = p[2 * j], d1 = p[2 * j + 1];
    h.u[j] = (d0 & 0xffffu) | (d1 << 16);
    l.u[j] = (d0 >> 16) | (d1 & 0xffff0000u);
  }
  hi = h.v;
  lo = l.v;
}

// C = A*B for 64x64 matrices stored as interleaved hi/lo dwords in LDS.
// B is treated as symmetric (true to ~1e-7 for all Newton operands), so the
// B-fragment is a contiguous row read like A. Split product: 3 MFMAs (drop lo*lo).
__device__ __forceinline__ void mm_core(floatx4 acc[4], const unsigned* A, const unsigned* B,
                                        int w, int quad, int lm) {
#pragma unroll
  for (int tj = 0; tj < 4; tj++) {
    floatx4 z = {0.f, 0.f, 0.f, 0.f};
    acc[tj] = z;
  }
#pragma unroll
  for (int kk = 0; kk < 2; kk++) {
    short8v Ahi, Alo;
    unpack8(&A[(16 * w + lm) * NSTRIDE + kk * 32 + quad * 8], Ahi, Alo);
#pragma unroll
    for (int tj = 0; tj < 4; tj++) {
      short8v Bhi, Blo;
      unpack8(&B[(16 * tj + lm) * NSTRIDE + kk * 32 + quad * 8], Bhi, Blo);
      acc[tj] = __builtin_amdgcn_mfma_f32_16x16x32_bf16(Ahi, Bhi, acc[tj], 0, 0, 0);
      acc[tj] = __builtin_amdgcn_mfma_f32_16x16x32_bf16(Ahi, Blo, acc[tj], 0, 0, 0);
      acc[tj] = __builtin_amdgcn_mfma_f32_16x16x32_bf16(Alo, Bhi, acc[tj], 0, 0, 0);
    }
  }
}

// ---------------- K1: mean + covariance partials ----------------
// grid 512 = 4 groups x 64 n x 2 halves; block 256 (4 waves).
// Per k-step: stage 64ch x 64hw fp32->bf16 tile, SYRK it with MFMA.
__global__ __launch_bounds__(256) void cov_kernel(const float* __restrict__ X,
                                                  float* __restrict__ cov_dst,
                                                  float* __restrict__ sum_dst, int use_part) {
  __shared__ unsigned short tile[64 * TSTRIDE];
  int bid = blockIdx.x;
  int g = bid >> 7;
  int rr_ = bid & 127;
  int n = rr_ >> 1;
  int h = rr_ & 1;
  int ks0 = h ? 25 : 0;
  int ks1 = h ? 49 : 25;
  int tid = threadIdx.x;
  int c = tid >> 2, q = tid & 3;
  int w = tid >> 6, lane = tid & 63, quad = lane >> 4, lm = lane & 15;

  floatx4 acc[4];
#pragma unroll
  for (int tj = 0; tj < 4; tj++) {
    floatx4 z = {0.f, 0.f, 0.f, 0.f};
    acc[tj] = z;
  }
  float fsum = 0.f;

  const float* xbase = X + ((size_t)(n * CCH + g * DCH + c)) * HWSZ;

  for (int ks = ks0; ks < ks1; ks++) {
    int k0 = ks * 64;
#pragma unroll
    for (int j = 0; j < 4; j++) {
      // per-instruction contiguous 64B across the 4 q-lanes of each channel
      int hw = j * 16 + q * 4;
      float4 v = *(const float4*)(xbase + k0 + hw);
      fsum += v.x + v.y + v.z + v.w;
      unsigned d0 = (unsigned)f2bf(v.x) | ((unsigned)f2bf(v.y) << 16);
      unsigned d1 = (unsigned)f2bf(v.z) | ((unsigned)f2bf(v.w) << 16);
      *(uint2*)&tile[c * TSTRIDE + hw] = make_uint2(d0, d1);
    }
    __syncthreads();
#pragma unroll
    for (int kk = 0; kk < 2; kk++) {
      F8U a;
      a.u2[0] = *(const uint2*)&tile[(16 * w + lm) * TSTRIDE + kk * 32 + quad * 8];
      a.u2[1] = *(const uint2*)&tile[(16 * w + lm) * TSTRIDE + kk * 32 + quad * 8 + 4];
#pragma unroll
      for (int tj = 0; tj < 4; tj++) {
        F8U b;
        b.u2[0] = *(const uint2*)&tile[(16 * tj + lm) * TSTRIDE + kk * 32 + quad * 8];
        b.u2[1] = *(const uint2*)&tile[(16 * tj + lm) * TSTRIDE + kk * 32 + quad * 8 + 4];
        acc[tj] = __builtin_amdgcn_mfma_f32_16x16x32_bf16(a.v, b.v, acc[tj], 0, 0, 0);
      }
    }
    __syncthreads();
  }

  if (use_part) {
    float* dst = cov_dst + (size_t)bid * 4096;
#pragma unroll
    for (int tj = 0; tj < 4; tj++) {
#pragma unroll
      for (int rr = 0; rr < 4; rr++) {
        dst[(16 * w + quad * 4 + rr) * 64 + 16 * tj + lm] = acc[tj][rr];
      }
    }
  } else {
    float* dst = cov_dst + (size_t)g * 4096;
#pragma unroll
    for (int tj = 0; tj < 4; tj++) {
#pragma unroll
      for (int rr = 0; rr < 4; rr++) {
        atomicAdd(&dst[(16 * w + quad * 4 + rr) * 64 + 16 * tj + lm], acc[tj][rr]);
      }
    }
  }

  // per-channel sums: reduce over the 4 q-threads of channel c (lane bits 0-1)
  fsum += __shfl_xor(fsum, 1);
  fsum += __shfl_xor(fsum, 2);
  if (q == 0) {
    if (use_part)
      sum_dst[(size_t)bid * 64 + c] = fsum;
    else
      atomicAdd(&sum_dst[g * 64 + c], fsum);
  }
}

// ---------------- K2: reduce partials, finalize Sigma ----------------
// grid 64 = 4 groups x 16 chunks of 256 Sigma elements
__global__ __launch_bounds__(256) void reduce_kernel(const float* __restrict__ cov_src,
                                                     const float* __restrict__ sum_src,
                                                     float* __restrict__ Sigma,
                                                     float* __restrict__ meanWS, int npart) {
  __shared__ float meanv[64];
  int g = blockIdx.x >> 4;
  int chunk = blockIdx.x & 15;
  int tid = threadIdx.x;
  if (tid < 64) {
    float s = 0.f;
    for (int i = 0; i < npart; i++) s += sum_src[((size_t)(g * npart + i)) * 64 + tid];
    float mn = s / (float)MTOT;
    meanv[tid] = mn;
    if (chunk == 0) meanWS[g * 64 + tid] = mn;
  }
  __syncthreads();
  int idx = chunk * 256 + tid;
  int d = idx >> 6, e = idx & 63;
  float cr = 0.f;
  for (int i = 0; i < npart; i++) cr += cov_src[((size_t)(g * npart + i)) * 4096 + idx];
  float sig = cr / (float)MTOT - meanv[d] * meanv[e] + (d == e ? EPSV : 0.f);
  Sigma[(size_t)g * 4096 + idx] = sig;
}

// ---------------- K3: Newton-Schulz, split-bf16 MFMA ----------------
// grid 4 (one block per group), block 256. LDS: 3 x 17.4KB interleaved matrices.
// Per iter: T1 = P*P; P <- P^3 (saving old P diag-positions in regs); P <- 1.5Pold - 0.5(P3*S)
__global__ __launch_bounds__(256) void newton_kernel(const float* __restrict__ Sigma,
                                                     unsigned short* __restrict__ wmB) {
  __shared__ unsigned Pb[64 * NSTRIDE];
  __shared__ unsigned T1b[64 * NSTRIDE];
  __shared__ unsigned Sb[64 * NSTRIDE];
  __shared__ float diag[64];
  int g = blockIdx.x;
  int tid = threadIdx.x;
  int w = tid >> 6, lane = tid & 63, quad = lane >> 4, lm = lane & 15;
  const float* Sg = Sigma + (size_t)g * 4096;

  if (tid < 64) diag[tid] = Sg[tid * 64 + tid];
  __syncthreads();
  float tr = 0.f;
  for (int i = 0; i < 64; i++) tr += diag[i];
  float rTr = 1.0f / tr;

  for (int idx = tid; idx < 4096; idx += 256) {
    int d = idx >> 6, e = idx & 63;
    Sb[d * NSTRIDE + e] = pack_hl(Sg[idx] * rTr);
    Pb[d * NSTRIDE + e] = (d == e) ? 0x00003f80u : 0u;  // identity (hi=1.0, lo=0)
  }
  __syncthreads();

  floatx4 acc[4];
  float pold[4][4];

  for (int t = 0; t < 10; t++) {
    // T1 = P*P
    mm_core(acc, Pb, Pb, w, quad, lm);
    __syncthreads();
#pragma unroll
    for (int tj = 0; tj < 4; tj++) {
#pragma unroll
      for (int rr = 0; rr < 4; rr++) {
        T1b[(16 * w + quad * 4 + rr) * NSTRIDE + 16 * tj + lm] = pack_hl(acc[tj][rr]);
      }
    }
    __syncthreads();
    // P3 = T1*P -> overwrite Pb; each lane saves its own old-P elements first
    mm_core(acc, T1b, Pb, w, quad, lm);
    __syncthreads();
#pragma unroll
    for (int tj = 0; tj < 4; tj++) {
#pragma unroll
      for (int rr = 0; rr < 4; rr++) {
        int a = (16 * w + quad * 4 + rr) * NSTRIDE + 16 * tj + lm;
        pold[tj][rr] = unpack_f(Pb[a]);
        Pb[a] = pack_hl(acc[tj][rr]);
      }
    }
    __syncthreads();
    // Pnew = 1.5*Pold - 0.5*(P3 * Sigma_N)
    mm_core(acc, Pb, Sb, w, quad, lm);
    __syncthreads();
#pragma unroll
    for (int tj = 0; tj < 4; tj++) {
#pragma unroll
      for (int rr = 0; rr < 4; rr++) {
        int a = (16 * w + quad * 4 + rr) * NSTRIDE + 16 * tj + lm;
        Pb[a] = pack_hl(1.5f * pold[tj][rr] - 0.5f * acc[tj][rr]);
      }
    }
    __syncthreads();
  }

  float sc = sqrtf(rTr);
  unsigned short* wg = wmB + (size_t)g * 4096;
#pragma unroll
  for (int tj = 0; tj < 4; tj++) {
#pragma unroll
    for (int rr = 0; rr < 4; rr++) {
      int row = 16 * w + quad * 4 + rr, col = 16 * tj + lm;
      wg[row * 64 + col] = f2bf(unpack_f(Pb[row * NSTRIDE + col]) * sc);
    }
  }
}

// ---------------- K4: apply whitening ----------------
// grid 512 like K1. wm A-frags preloaded in registers; xc tile staged transposed
// ([sample][channel]) so B-fragment reads are contiguous row reads.
__global__ __launch_bounds__(256) void apply_kernel(
    const float* __restrict__ X, const unsigned short* __restrict__ wmB,
    const float* __restrict__ meanWS, const float* __restrict__ weight,
    const float* __restrict__ bias, float* __restrict__ out) {
  __shared__ unsigned short T[64 * TSTRIDE];
  __shared__ float meanv[64];
  __shared__ float wv[64];
  __shared__ float bv[64];
  int bid = blockIdx.x;
  int g = bid >> 7;
  int rr_ = bid & 127;
  int n = rr_ >> 1;
  int h = rr_ & 1;
  int ks0 = h ? 25 : 0;
  int ks1 = h ? 49 : 25;
  int tid = threadIdx.x;
  int w = tid >> 6, lane = tid & 63, quad = lane >> 4, lm = lane & 15;
  int sl = tid & 63;   // staging: sample within tile
  int cg = tid >> 6;   // staging: channel group of 16

  if (tid < 64) {
    meanv[tid] = meanWS[g * 64 + tid];
    wv[tid] = weight[g * 64 + tid];
    bv[tid] = bias[g * 64 + tid];
  }
  // preload wm A-fragments (rows 16w..16w+15, all K) -- lives in regs for whole block
  F8U afrag[2];
#pragma unroll
  for (int kk = 0; kk < 2; kk++) {
    const uint2* p =
        (const uint2*)&wmB[(size_t)g * 4096 + (16 * w + lm) * 64 + kk * 32 + quad * 8];
    afrag[kk].u2[0] = p[0];
    afrag[kk].u2[1] = p[1];
  }
  __syncthreads();

  const float* xg = X + ((size_t)(n * CCH + g * DCH)) * HWSZ;
  float* og = out + ((size_t)(n * CCH + g * DCH)) * HWSZ;

  for (int ks = ks0; ks < ks1; ks++) {
    int k0 = ks * 64;
    // stage transposed: thread reads 16 channels (coalesced across 64 sl lanes)
    {
      const float* xp = xg + (size_t)(cg * 16) * HWSZ + k0 + sl;
      unsigned dws[8];
#pragma unroll
      for (int jp = 0; jp < 8; jp++) {
        float v0 = xp[(size_t)(2 * jp) * HWSZ] - meanv[cg * 16 + 2 * jp];
        float v1 = xp[(size_t)(2 * jp + 1) * HWSZ] - meanv[cg * 16 + 2 * jp + 1];
        dws[jp] = (unsigned)f2bf(v0) | ((unsigned)f2bf(v1) << 16);
      }
#pragma unroll
      for (int p2 = 0; p2 < 4; p2++) {
        *(uint2*)&T[sl * TSTRIDE + cg * 16 + p2 * 4] = make_uint2(dws[2 * p2], dws[2 * p2 + 1]);
      }
    }
    __syncthreads();

    floatx4 acc[4];
#pragma unroll
    for (int tj = 0; tj < 4; tj++) {
      floatx4 z = {0.f, 0.f, 0.f, 0.f};
      acc[tj] = z;
    }
#pragma unroll
    for (int kk = 0; kk < 2; kk++) {
#pragma unroll
      for (int tj = 0; tj < 4; tj++) {
        F8U b;
        b.u2[0] = *(const uint2*)&T[(16 * tj + lm) * TSTRIDE + kk * 32 + quad * 8];
        b.u2[1] = *(const uint2*)&T[(16 * tj + lm) * TSTRIDE + kk * 32 + quad * 8 + 4];
        acc[tj] = __builtin_amdgcn_mfma_f32_16x16x32_bf16(afrag[kk].v, b.v, acc[tj], 0, 0, 0);
      }
    }
    // epilogue: scale+shift, store (16-lane 64B segments per reg)
#pragma unroll
    for (int tj = 0; tj < 4; tj++) {
#pragma unroll
      for (int rr = 0; rr < 4; rr++) {
        int cc = 16 * w + quad * 4 + rr;
        og[(size_t)cc * HWSZ + k0 + 16 * tj + lm] = acc[tj][rr] * wv[cc] + bv[cc];
      }
    }
    __syncthreads();
  }
}

extern "C" void kernel_launch(void* const* d_in, const int* in_sizes, int n_in, void* d_out,
                              int out_size, void* d_ws, size_t ws_size, hipStream_t stream) {
  (void)in_sizes;
  (void)n_in;
  (void)out_size;
  const float* X = (const float*)d_in[0];
  const float* weight = (const float*)d_in[1];
  const float* bias = (const float*)d_in[2];
  float* out = (float*)d_out;
  char* ws = (char*)d_ws;

  // ws layout (bytes):
  //   0       : Sigma        4*4096 f32   (65536)
  //   65536   : mean         4*64  f32    (1024)
  //   66560   : wmB          4*4096 bf16  (32768)
  //   99328   : cov partials 512*4096 f32 (8388608)  [or 4*4096 atomic accum]
  //   8487936 : sum partials 512*64 f32   (131072)   [or 4*64 atomic accum @164864]
  float* Sigma = (float*)(ws + 0);
  float* meanWS = (float*)(ws + 65536);
  unsigned short* wmB = (unsigned short*)(ws + 66560);
  float* cov_dst = (float*)(ws + 99328);
  const size_t need_part = 99328u + 8388608u + 131072u;
  int use_part = (ws_size >= need_part) ? 1 : 0;
  float* sum_dst =
      use_part ? (float*)(ws + 99328 + 8388608) : (float*)(ws + 99328 + 65536);
  int npart = use_part ? 128 : 1;

  if (!use_part) {
    // atomic accumulators must start at zero (ws is poisoned before each launch)
    hipMemsetAsync(cov_dst, 0, 65536 + 1024, stream);
  }

  cov_kernel<<<dim3(512), dim3(256), 0, stream>>>(X, cov_dst, sum_dst, use_part);
  reduce_kernel<<<dim3(64), dim3(256), 0, stream>>>(cov_dst, sum_dst, Sigma, meanWS, npart);
  newton_kernel<<<dim3(4), dim3(256), 0, stream>>>(Sigma, wmB);
  apply_kernel<<<dim3(512), dim3(256), 0, stream>>>(X, wmB, meanWS, weight, bias, out);
}

// Round 2
// 454.183 us; speedup vs baseline: 1.1032x; 1.1032x over previous
//
#include <hip/hip_runtime.h>

// IterNorm (ZCA whitening via Newton-Schulz) for X[64,256,56,56] fp32, d=64, g=4, T=10.
//
//  K1 cov_kernel   : fused mean+cov partials, bf16 MFMA SYRK. grid 1024, reg-prefetch
//                    pipeline with lgkm-only barriers (global loads stay in flight).
//  K2a mean_kernel : reduce per-block channel sums -> mean. grid 4.
//  K2b sigma_kernel: reduce cov partials -> Sigma = E[xx]/m - mu mu^T + eps I. grid 256.
//  K3 newton_kernel: 10 Newton iters, split-bf16 in SEPARATE hi/lo LDS planes (no
//                    unpack VALU), symmetric-transpose C writes (b64), 3 barriers/iter.
//  K4 apply_kernel : out = (wm @ (x-mean)) * weight + bias. grid 1024, same pipeline.
//
// MFMA 16x16x32 bf16 layouts (verified round 1):
//   A: lane l holds A[m=l&15][k=(l>>4)*8+j]   B: lane l holds B[k=(l>>4)*8+j][n=l&15]
//   C/D: lane l reg r -> row=(l>>4)*4+r, col=l&15

#define HWSZ 3136
#define CCH 256
#define DCH 64
#define MTOT (64 * HWSZ) /* 200704 */
#define EPSV 1e-5f
#define TST 68 /* tile row stride in shorts; uint2 accesses stay 8B-aligned */
#define NST 68

typedef __attribute__((ext_vector_type(8))) short short8v;
typedef __attribute__((ext_vector_type(4))) float floatx4;

union F8U {
  short8v v;
  unsigned u[4];
  uint2 u2[2];
};

__device__ __forceinline__ unsigned short f2bf(float f) {
  unsigned u = __float_as_uint(f);
  u += 0x7fffu + ((u >> 16) & 1u);
  return (unsigned short)(u >> 16);
}
__device__ __forceinline__ float bf2f(unsigned short h) {
  return __uint_as_float(((unsigned)h) << 16);
}

// Workgroup barrier that waits LDS only: leaves global loads/stores in flight
// (__syncthreads would emit s_waitcnt vmcnt(0) and kill the prefetch overlap).
__device__ __forceinline__ void sync_lds() {
  asm volatile("s_waitcnt lgkmcnt(0)\n\ts_barrier" ::: "memory");
}

// ---------------- K1: mean + covariance partials ----------------
// grid 1024 = 4 groups x 64 n x 4 hw-quarters (12/12/12/13 k-steps of 64 hw).
__global__ __launch_bounds__(256) void cov_kernel(const float* __restrict__ X,
                                                  float* __restrict__ cov_dst,
                                                  float* __restrict__ sum_dst, int use_part) {
  __shared__ unsigned short tile[64 * TST];
  int bid = blockIdx.x;
  int g = bid >> 8;
  int nn = (bid >> 2) & 63;
  int qh = bid & 3;
  int ks0 = (qh * 49) >> 2;       // 0,12,24,36
  int ks1 = ((qh + 1) * 49) >> 2; // 12,24,36,49
  int tid = threadIdx.x;
  int c = tid >> 2, q = tid & 3;
  int w = tid >> 6, lane = tid & 63, quad = lane >> 4, lm = lane & 15;

  floatx4 acc[4];
#pragma unroll
  for (int tj = 0; tj < 4; tj++) {
    floatx4 z = {0.f, 0.f, 0.f, 0.f};
    acc[tj] = z;
  }
  float fsum = 0.f;

  const float* xbase = X + ((size_t)(nn * CCH + g * DCH + c)) * HWSZ;

  float4 v[4];
  {
    int k0 = ks0 * 64;
#pragma unroll
    for (int j = 0; j < 4; j++) v[j] = *(const float4*)(xbase + k0 + j * 16 + q * 4);
  }

  for (int ks = ks0; ks < ks1; ks++) {
    // stage current tile (consumes prefetch regs)
#pragma unroll
    for (int j = 0; j < 4; j++) {
      float4 t = v[j];
      fsum += t.x + t.y + t.z + t.w;
      unsigned d0 = (unsigned)f2bf(t.x) | ((unsigned)f2bf(t.y) << 16);
      unsigned d1 = (unsigned)f2bf(t.z) | ((unsigned)f2bf(t.w) << 16);
      *(uint2*)&tile[c * TST + j * 16 + q * 4] = make_uint2(d0, d1);
    }
    sync_lds();
    // prefetch next tile -- overlaps the MFMA phase below
    if (ks + 1 < ks1) {
      int k0 = (ks + 1) * 64;
#pragma unroll
      for (int j = 0; j < 4; j++) v[j] = *(const float4*)(xbase + k0 + j * 16 + q * 4);
    }
#pragma unroll
    for (int kk = 0; kk < 2; kk++) {
      F8U a;
      a.u2[0] = *(const uint2*)&tile[(16 * w + lm) * TST + kk * 32 + quad * 8];
      a.u2[1] = *(const uint2*)&tile[(16 * w + lm) * TST + kk * 32 + quad * 8 + 4];
#pragma unroll
      for (int tj = 0; tj < 4; tj++) {
        F8U b;
        b.u2[0] = *(const uint2*)&tile[(16 * tj + lm) * TST + kk * 32 + quad * 8];
        b.u2[1] = *(const uint2*)&tile[(16 * tj + lm) * TST + kk * 32 + quad * 8 + 4];
        acc[tj] = __builtin_amdgcn_mfma_f32_16x16x32_bf16(a.v, b.v, acc[tj], 0, 0, 0);
      }
    }
    sync_lds(); // reads done (consumed by MFMA); next iter may overwrite tile
  }

  int pidx = bid & 255;
  if (use_part) {
    float* dst = cov_dst + ((size_t)g * 256 + pidx) * 4096;
#pragma unroll
    for (int tj = 0; tj < 4; tj++)
#pragma unroll
      for (int rr = 0; rr < 4; rr++)
        dst[(16 * w + quad * 4 + rr) * 64 + 16 * tj + lm] = acc[tj][rr];
  } else {
    float* dst = cov_dst + (size_t)g * 4096;
#pragma unroll
    for (int tj = 0; tj < 4; tj++)
#pragma unroll
      for (int rr = 0; rr < 4; rr++)
        atomicAdd(&dst[(16 * w + quad * 4 + rr) * 64 + 16 * tj + lm], acc[tj][rr]);
  }

  fsum += __shfl_xor(fsum, 1);
  fsum += __shfl_xor(fsum, 2);
  if (q == 0) {
    if (use_part)
      sum_dst[((size_t)g * 256 + pidx) * 64 + c] = fsum;
    else
      atomicAdd(&sum_dst[g * 64 + c], fsum);
  }
}

// ---------------- K2a: channel means ----------------
__global__ __launch_bounds__(256) void mean_kernel(const float* __restrict__ sum_part,
                                                   float* __restrict__ meanWS, int npart) {
  __shared__ float red[256];
  int g = blockIdx.x, tid = threadIdx.x;
  int c = tid & 63, p0 = tid >> 6;
  float s0 = 0.f, s1 = 0.f;
  for (int p = p0; p + 4 < npart; p += 8) {
    s0 += sum_part[((size_t)g * npart + p) * 64 + c];
    s1 += sum_part[((size_t)g * npart + p + 4) * 64 + c];
  }
  for (int p = p0 + ((npart - p0 + 7) / 8) * 8 - 8 + 8; p < npart; p += 4) s0 += 0.f; // no-op guard
  // handle tail (npart multiple of 4 in both paths; loop above covers pairs)
  if (((npart >> 2) & 1) && (p0 + ((npart >> 2) - 1) * 4 < npart)) {
    int p = ((npart >> 2) - 1) * 4 + p0;
    if (p < npart) s0 += sum_part[((size_t)g * npart + p) * 64 + c];
  }
  red[tid] = s0 + s1;
  __syncthreads();
  if (tid < 64)
    meanWS[g * 64 + tid] =
        (red[tid] + red[tid + 64] + red[tid + 128] + red[tid + 192]) / (float)MTOT;
}

// ---------------- K2b: Sigma ----------------
// grid 256 = 4 groups x 64 rows; 4 threads per element, npart/4 parts each.
__global__ __launch_bounds__(256) void sigma_kernel(const float* __restrict__ cov_part,
                                                    const float* __restrict__ meanWS,
                                                    float* __restrict__ Sigma, int npart) {
  __shared__ float red[256];
  int b = blockIdx.x;
  int g = b >> 6, r = b & 63;
  int tid = threadIdx.x;
  int e = tid & 63, p0 = tid >> 6;
  float s = 0.f;
  for (int p = p0; p < npart; p += 4)
    s += cov_part[((size_t)g * npart + p) * 4096 + r * 64 + e];
  red[tid] = s;
  __syncthreads();
  if (tid < 64) {
    float tot = red[tid] + red[tid + 64] + red[tid + 128] + red[tid + 192];
    float mr = meanWS[g * 64 + r], me = meanWS[g * 64 + tid];
    Sigma[(size_t)g * 4096 + r * 64 + tid] =
        tot / (float)MTOT - mr * me + (r == tid ? EPSV : 0.f);
  }
}

// ---------------- K3: Newton-Schulz, hi/lo planes ----------------
// All operands symmetric & commuting: store value(r,c) at plane[c*NST+r]
// (transposed == itself), so C/D writes are column-contiguous b64 stores and
// A/B fragment reads are contiguous row reads. 3 mms, 3 barriers per iter.
__device__ __forceinline__ void mm_planes(floatx4 acc[4], const unsigned short* Ah,
                                          const unsigned short* Al, const unsigned short* Bh,
                                          const unsigned short* Bl, int w, int quad, int lm) {
#pragma unroll
  for (int tj = 0; tj < 4; tj++) {
    floatx4 z = {0.f, 0.f, 0.f, 0.f};
    acc[tj] = z;
  }
#pragma unroll
  for (int kk = 0; kk < 2; kk++) {
    int abase = (16 * w + lm) * NST + kk * 32 + quad * 8;
    F8U ahi, alo;
    ahi.u2[0] = *(const uint2*)&Ah[abase];
    ahi.u2[1] = *(const uint2*)&Ah[abase + 4];
    alo.u2[0] = *(const uint2*)&Al[abase];
    alo.u2[1] = *(const uint2*)&Al[abase + 4];
#pragma unroll
    for (int tj = 0; tj < 4; tj++) {
      int bbase = (16 * tj + lm) * NST + kk * 32 + quad * 8;
      F8U bhi, blo;
      bhi.u2[0] = *(const uint2*)&Bh[bbase];
      bhi.u2[1] = *(const uint2*)&Bh[bbase + 4];
      blo.u2[0] = *(const uint2*)&Bl[bbase];
      blo.u2[1] = *(const uint2*)&Bl[bbase + 4];
      acc[tj] = __builtin_amdgcn_mfma_f32_16x16x32_bf16(ahi.v, bhi.v, acc[tj], 0, 0, 0);
      acc[tj] = __builtin_amdgcn_mfma_f32_16x16x32_bf16(ahi.v, blo.v, acc[tj], 0, 0, 0);
      acc[tj] = __builtin_amdgcn_mfma_f32_16x16x32_bf16(alo.v, bhi.v, acc[tj], 0, 0, 0);
    }
  }
}

__device__ __forceinline__ void store_tr(const floatx4 acc[4], unsigned short* H,
                                         unsigned short* L, int w, int quad, int lm) {
#pragma unroll
  for (int tj = 0; tj < 4; tj++) {
    unsigned short hs[4], ls[4];
#pragma unroll
    for (int rr = 0; rr < 4; rr++) {
      float f = acc[tj][rr];
      hs[rr] = f2bf(f);
      ls[rr] = f2bf(f - bf2f(hs[rr]));
    }
    int a = (16 * tj + lm) * NST + 16 * w + quad * 4;
    *(uint2*)&H[a] = make_uint2((unsigned)hs[0] | ((unsigned)hs[1] << 16),
                                (unsigned)hs[2] | ((unsigned)hs[3] << 16));
    *(uint2*)&L[a] = make_uint2((unsigned)ls[0] | ((unsigned)ls[1] << 16),
                                (unsigned)ls[2] | ((unsigned)ls[3] << 16));
  }
}

__global__ __launch_bounds__(256) void newton_kernel(const float* __restrict__ Sigma,
                                                     unsigned short* __restrict__ wmB) {
  __shared__ unsigned short Ph[64 * NST], Pl[64 * NST];
  __shared__ unsigned short Sh[64 * NST], Sl[64 * NST];
  __shared__ unsigned short Th[64 * NST], Tl[64 * NST];
  __shared__ unsigned short Uh[64 * NST], Ul[64 * NST];
  __shared__ float diag[64];
  int g = blockIdx.x, tid = threadIdx.x;
  int w = tid >> 6, lane = tid & 63, quad = lane >> 4, lm = lane & 15;
  const float* Sg = Sigma + (size_t)g * 4096;

  if (tid < 64) diag[tid] = Sg[tid * 65];
  __syncthreads();
  float tr = 0.f;
#pragma unroll 8
  for (int i = 0; i < 64; i++) tr += diag[i];
  float rTr = 1.0f / tr;

  for (int idx = tid; idx < 4096; idx += 256) {
    int r = idx >> 6, c2 = idx & 63;
    float vv = Sg[idx] * rTr;
    unsigned short h = f2bf(vv);
    Sh[r * NST + c2] = h;
    Sl[r * NST + c2] = f2bf(vv - bf2f(h));
    Ph[r * NST + c2] = (r == c2) ? (unsigned short)0x3f80 : (unsigned short)0;
    Pl[r * NST + c2] = 0;
  }
  sync_lds();

  floatx4 acc[4];
  float pf[4][4];

  for (int t = 0; t < 10; t++) {
    mm_planes(acc, Ph, Pl, Ph, Pl, w, quad, lm); // T = P*P
    store_tr(acc, Th, Tl, w, quad, lm);
    sync_lds();
    mm_planes(acc, Th, Tl, Ph, Pl, w, quad, lm); // U = P^3
    store_tr(acc, Uh, Ul, w, quad, lm);
    sync_lds();
    mm_planes(acc, Uh, Ul, Sh, Sl, w, quad, lm); // P^3 * Sigma_N
    // newP = 1.5*P - 0.5*acc ; each lane owns exactly the elements it rewrites
#pragma unroll
    for (int tj = 0; tj < 4; tj++) {
      int a = (16 * tj + lm) * NST + 16 * w + quad * 4;
      uint2 ho = *(const uint2*)&Ph[a];
      uint2 lo = *(const uint2*)&Pl[a];
      unsigned short hs[4] = {(unsigned short)(ho.x & 0xffff), (unsigned short)(ho.x >> 16),
                              (unsigned short)(ho.y & 0xffff), (unsigned short)(ho.y >> 16)};
      unsigned short lss[4] = {(unsigned short)(lo.x & 0xffff), (unsigned short)(lo.x >> 16),
                               (unsigned short)(lo.y & 0xffff), (unsigned short)(lo.y >> 16)};
      unsigned short nh[4], nl[4];
#pragma unroll
      for (int rr = 0; rr < 4; rr++) {
        float pown = bf2f(hs[rr]) + bf2f(lss[rr]);
        float f = 1.5f * pown - 0.5f * acc[tj][rr];
        pf[tj][rr] = f;
        nh[rr] = f2bf(f);
        nl[rr] = f2bf(f - bf2f(nh[rr]));
      }
      *(uint2*)&Ph[a] = make_uint2((unsigned)nh[0] | ((unsigned)nh[1] << 16),
                                   (unsigned)nh[2] | ((unsigned)nh[3] << 16));
      *(uint2*)&Pl[a] = make_uint2((unsigned)nl[0] | ((unsigned)nl[1] << 16),
                                   (unsigned)nl[2] | ((unsigned)nl[3] << 16));
    }
    sync_lds();
  }

  // wm = P * sqrt(rTr), written straight from the last iteration's registers
  float sc = sqrtf(rTr);
  unsigned short* wg = wmB + (size_t)g * 4096;
#pragma unroll
  for (int tj = 0; tj < 4; tj++)
#pragma unroll
    for (int rr = 0; rr < 4; rr++) {
      int row = 16 * w + quad * 4 + rr, col = 16 * tj + lm;
      wg[row * 64 + col] = f2bf(pf[tj][rr] * sc);
    }
}

// ---------------- K4: apply whitening ----------------
__global__ __launch_bounds__(256) void apply_kernel(
    const float* __restrict__ X, const unsigned short* __restrict__ wmB,
    const float* __restrict__ meanWS, const float* __restrict__ weight,
    const float* __restrict__ bias, float* __restrict__ out) {
  __shared__ unsigned short T[64 * TST];
  __shared__ float meanv[64], wv[64], bv[64];
  int bid = blockIdx.x;
  int g = bid >> 8;
  int nn = (bid >> 2) & 63;
  int qh = bid & 3;
  int ks0 = (qh * 49) >> 2;
  int ks1 = ((qh + 1) * 49) >> 2;
  int tid = threadIdx.x;
  int w = tid >> 6, lane = tid & 63, quad = lane >> 4, lm = lane & 15;
  int sl = tid & 63;
  int cg = tid >> 6;

  if (tid < 64) {
    meanv[tid] = meanWS[g * 64 + tid];
    wv[tid] = weight[g * 64 + tid];
    bv[tid] = bias[g * 64 + tid];
  }
  F8U afrag[2];
#pragma unroll
  for (int kk = 0; kk < 2; kk++) {
    const uint2* p =
        (const uint2*)&wmB[(size_t)g * 4096 + (16 * w + lm) * 64 + kk * 32 + quad * 8];
    afrag[kk].u2[0] = p[0];
    afrag[kk].u2[1] = p[1];
  }
  __syncthreads();

  const float* xg = X + ((size_t)(nn * CCH + g * DCH)) * HWSZ;
  float* og = out + ((size_t)(nn * CCH + g * DCH)) * HWSZ;
  const float* xs = xg + (size_t)(cg * 16) * HWSZ + sl;

  float vv[16];
  {
    int k0 = ks0 * 64;
#pragma unroll
    for (int jp = 0; jp < 16; jp++) vv[jp] = xs[(size_t)jp * HWSZ + k0];
  }

  for (int ks = ks0; ks < ks1; ks++) {
    int k0 = ks * 64;
    // pack current tile (transposed [sample][channel]), consuming prefetch regs
#pragma unroll
    for (int p2 = 0; p2 < 4; p2++) {
      unsigned d0 = (unsigned)f2bf(vv[4 * p2] - meanv[cg * 16 + 4 * p2]) |
                    ((unsigned)f2bf(vv[4 * p2 + 1] - meanv[cg * 16 + 4 * p2 + 1]) << 16);
      unsigned d1 = (unsigned)f2bf(vv[4 * p2 + 2] - meanv[cg * 16 + 4 * p2 + 2]) |
                    ((unsigned)f2bf(vv[4 * p2 + 3] - meanv[cg * 16 + 4 * p2 + 3]) << 16);
      *(uint2*)&T[sl * TST + cg * 16 + p2 * 4] = make_uint2(d0, d1);
    }
    sync_lds();
    // prefetch next tile -- overlaps MFMA + epilogue stores
    if (ks + 1 < ks1) {
      int k0n = (ks + 1) * 64;
#pragma unroll
      for (int jp = 0; jp < 16; jp++) vv[jp] = xs[(size_t)jp * HWSZ + k0n];
    }
    floatx4 acc[4];
#pragma unroll
    for (int tj = 0; tj < 4; tj++) {
      floatx4 z = {0.f, 0.f, 0.f, 0.f};
      acc[tj] = z;
    }
#pragma unroll
    for (int kk = 0; kk < 2; kk++) {
#pragma unroll
      for (int tj = 0; tj < 4; tj++) {
        F8U b;
        b.u2[0] = *(const uint2*)&T[(16 * tj + lm) * TST + kk * 32 + quad * 8];
        b.u2[1] = *(const uint2*)&T[(16 * tj + lm) * TST + kk * 32 + quad * 8 + 4];
        acc[tj] = __builtin_amdgcn_mfma_f32_16x16x32_bf16(afrag[kk].v, b.v, acc[tj], 0, 0, 0);
      }
    }
#pragma unroll
    for (int tj = 0; tj < 4; tj++)
#pragma unroll
      for (int rr = 0; rr < 4; rr++) {
        int cc = 16 * w + quad * 4 + rr;
        og[(size_t)cc * HWSZ + k0 + 16 * tj + lm] = acc[tj][rr] * wv[cc] + bv[cc];
      }
    sync_lds(); // LDS reads consumed; stores stay in flight
  }
}

extern "C" void kernel_launch(void* const* d_in, const int* in_sizes, int n_in, void* d_out,
                              int out_size, void* d_ws, size_t ws_size, hipStream_t stream) {
  (void)in_sizes;
  (void)n_in;
  (void)out_size;
  const float* X = (const float*)d_in[0];
  const float* weight = (const float*)d_in[1];
  const float* bias = (const float*)d_in[2];
  float* out = (float*)d_out;
  char* ws = (char*)d_ws;

  // ws layout: Sigma @0 (64KB) | mean @65536 (1KB) | wmB @66560 (32KB)
  //            cov partials @99328 (4*256*4096*4 = 16MB) | sum partials (+16777216, 256KB)
  float* Sigma = (float*)(ws + 0);
  float* meanWS = (float*)(ws + 65536);
  unsigned short* wmB = (unsigned short*)(ws + 66560);
  float* cov_dst = (float*)(ws + 99328);
  const size_t need_part = 99328u + 16777216u + 262144u;
  int use_part = (ws_size >= need_part) ? 1 : 0;
  float* sum_dst =
      use_part ? (float*)(ws + 99328 + 16777216) : (float*)(ws + 99328 + 65536);
  int npart = use_part ? 256 : 1;

  if (!use_part) {
    hipMemsetAsync(cov_dst, 0, 65536 + 1024, stream);
  }

  cov_kernel<<<dim3(1024), dim3(256), 0, stream>>>(X, cov_dst, sum_dst, use_part);
  mean_kernel<<<dim3(4), dim3(256), 0, stream>>>(sum_dst, meanWS, npart);
  sigma_kernel<<<dim3(256), dim3(256), 0, stream>>>(cov_dst, meanWS, Sigma, npart);
  newton_kernel<<<dim3(4), dim3(256), 0, stream>>>(Sigma, wmB);
  apply_kernel<<<dim3(1024), dim3(256), 0, stream>>>(X, wmB, meanWS, weight, bias, out);
}